// Round 11
// baseline (3621.191 us; speedup 1.0000x reference)
//
#include <hip/hip_runtime.h>
#include <math.h>

constexpr int kB = 512, kENC = 64, kH = 512, kV = 42, kSEQ = 128;
constexpr int kWPitch = 520;                    // bf16 LDS row pitch (bank-skewed)
constexpr int kWRows  = 96;                     // 48 T0 (Wc|whh1) + 24 whh0 + 24 wih1
constexpr int kZPad   = kWRows * kWPitch;       // 49920: 32 bf16 zeros
constexpr int kCsAByte = (kZPad + 32) * 2;      // 99904
// CsA 7680 f32 + CsB 3840 f32 + bias table 120 f32
constexpr int kLdsBytes = kCsAByte + 30720 + 15360 + 480;  // 146464

typedef __attribute__((ext_vector_type(8))) short bf16x8;
typedef __attribute__((ext_vector_type(4))) float f32x4;
typedef unsigned long long u64;

__device__ __forceinline__ unsigned short f2bf(float x) {
  union { float f; unsigned u; } c; c.f = x;
  unsigned r = c.u + 0x7FFFu + ((c.u >> 16) & 1u);
  return (unsigned short)(r >> 16);
}
__device__ __forceinline__ float sigm(float x) { return 1.f / (1.f + expf(-x)); }

// Batched LLC-coherent A-row fetch: 16x global_load_dwordx4 sc0 sc1 (L1/L2
// bypass, coherent point) in ONE asm block, vmcnt(0) inside. R2-proven: 16
// loads in flight -> one LLC latency per phase instead of 16. R9 proved the
// L2-cached (sc0-only + buffer_inv) variant REGRESSES. Keep sc0 sc1.
__device__ __forceinline__ void ld_row16(const unsigned short* p, bf16x8 (&r)[16]) {
  asm volatile(
    "global_load_dwordx4 %0, %16, off sc0 sc1\n\t"
    "global_load_dwordx4 %1, %16, off offset:64 sc0 sc1\n\t"
    "global_load_dwordx4 %2, %16, off offset:128 sc0 sc1\n\t"
    "global_load_dwordx4 %3, %16, off offset:192 sc0 sc1\n\t"
    "global_load_dwordx4 %4, %16, off offset:256 sc0 sc1\n\t"
    "global_load_dwordx4 %5, %16, off offset:320 sc0 sc1\n\t"
    "global_load_dwordx4 %6, %16, off offset:384 sc0 sc1\n\t"
    "global_load_dwordx4 %7, %16, off offset:448 sc0 sc1\n\t"
    "global_load_dwordx4 %8, %16, off offset:512 sc0 sc1\n\t"
    "global_load_dwordx4 %9, %16, off offset:576 sc0 sc1\n\t"
    "global_load_dwordx4 %10, %16, off offset:640 sc0 sc1\n\t"
    "global_load_dwordx4 %11, %16, off offset:704 sc0 sc1\n\t"
    "global_load_dwordx4 %12, %16, off offset:768 sc0 sc1\n\t"
    "global_load_dwordx4 %13, %16, off offset:832 sc0 sc1\n\t"
    "global_load_dwordx4 %14, %16, off offset:896 sc0 sc1\n\t"
    "global_load_dwordx4 %15, %16, off offset:960 sc0 sc1\n\t"
    "s_waitcnt vmcnt(0)"
    : "=&v"(r[0]), "=&v"(r[1]), "=&v"(r[2]), "=&v"(r[3]),
      "=&v"(r[4]), "=&v"(r[5]), "=&v"(r[6]), "=&v"(r[7]),
      "=&v"(r[8]), "=&v"(r[9]), "=&v"(r[10]), "=&v"(r[11]),
      "=&v"(r[12]), "=&v"(r[13]), "=&v"(r[14]), "=&v"(r[15])
    : "v"(p)
    : "memory");
}

// agent-scope (LLC-coherent, L1/L2-bypass) h-state store (R8: coalesced
// staging is a regression — the fabric already write-combines this scatter).
__device__ __forceinline__ void st_h2(unsigned short* p, unsigned short v) {
  __hip_atomic_store(p, v, __ATOMIC_RELAXED, __HIP_MEMORY_SCOPE_AGENT);
}

// LEADER-AGGREGATED mg-group barrier (R6's design, never actually HW-tested —
// R6/R7 failed on an unrelated uint4-asm compile error):
// - arrival: each block release-stores its own padded slot (1 store, no RMW).
// - leader (jg==0): wave0's 64 lanes poll one slot each; when all >= ev,
//   lane 0 release-stores the per-mg flag.
// - others: lane 0 polls ONLY the shared flag line.
// Rationale: the flat barrier's poll storm (256 wave0s x 64 slot-lines per
// ~900cy dependent-load period ~= 2 TB/s of LLC poll traffic) overlaps and
// inflates laggard/leader data loads at every barrier. This topology cuts
// poll traffic ~130x for ~+0.5us critical path (one extra flag hop).
__device__ __forceinline__ void mg_barrier(unsigned* bar, unsigned ev, int mg,
                                           int jg, int wave, int lane) {
  __syncthreads();
  if (wave == 0) {
    if (lane == 0)
      __hip_atomic_store(&bar[(mg * 64 + jg) * 16], ev,
                         __ATOMIC_RELEASE, __HIP_MEMORY_SCOPE_AGENT);
    unsigned* flag = &bar[4096 + mg * 16];
    if (jg == 0) {
      const unsigned* sl = &bar[(mg * 64 + lane) * 16];
      while (__hip_atomic_load(sl, __ATOMIC_RELAXED, __HIP_MEMORY_SCOPE_AGENT) < ev)
        __builtin_amdgcn_s_sleep(1);
      if (lane == 0)
        __hip_atomic_store(flag, ev, __ATOMIC_RELEASE, __HIP_MEMORY_SCOPE_AGENT);
      (void)__hip_atomic_load(sl, __ATOMIC_ACQUIRE, __HIP_MEMORY_SCOPE_AGENT);
    } else if (lane == 0) {
      while (__hip_atomic_load(flag, __ATOMIC_RELAXED, __HIP_MEMORY_SCOPE_AGENT) < ev)
        __builtin_amdgcn_s_sleep(1);
      (void)__hip_atomic_load(flag, __ATOMIC_ACQUIRE, __HIP_MEMORY_SCOPE_AGENT);
    }
  }
  __syncthreads();
}

// ---------------- generic SGEMM: C[M,N] = act(A[M,K] @ W[N,K]^T + bias[N]) ----
template<bool RELU>
__global__ __launch_bounds__(256) void gemm_bias(const float* __restrict__ A,
    const float* __restrict__ W, const float* __restrict__ bias,
    float* __restrict__ C, int M, int N, int K)
{
  __shared__ float As[16][68];
  __shared__ float Bs[16][68];
  const int tid = threadIdx.x;
  const int n0 = blockIdx.x * 64;
  const int m0 = blockIdx.y * 64;
  const int tx = tid & 15;
  const int ty = tid >> 4;
  const int lr = tid >> 2;
  const int lk = (tid & 3) << 2;
  float acc[4][4] = {};
  for (int kc = 0; kc < K; kc += 16) {
    const float4 va = *(const float4*)(A + (size_t)(m0 + lr) * K + kc + lk);
    const float4 vb = *(const float4*)(W + (size_t)(n0 + lr) * K + kc + lk);
    __syncthreads();
    As[lk+0][lr] = va.x; As[lk+1][lr] = va.y; As[lk+2][lr] = va.z; As[lk+3][lr] = va.w;
    Bs[lk+0][lr] = vb.x; Bs[lk+1][lr] = vb.y; Bs[lk+2][lr] = vb.z; Bs[lk+3][lr] = vb.w;
    __syncthreads();
#pragma unroll
    for (int k = 0; k < 16; ++k) {
      const float4 a = *(const float4*)&As[k][ty << 2];
      const float4 b = *(const float4*)&Bs[k][tx << 2];
      const float av[4] = {a.x, a.y, a.z, a.w};
      const float bv[4] = {b.x, b.y, b.z, b.w};
#pragma unroll
      for (int i = 0; i < 4; ++i)
#pragma unroll
        for (int jj = 0; jj < 4; ++jj) acc[i][jj] = fmaf(av[i], bv[jj], acc[i][jj]);
    }
  }
  const int cn = n0 + (tx << 2);
  const float4 b4 = *(const float4*)&bias[cn];
  const float bvv[4] = {b4.x, b4.y, b4.z, b4.w};
#pragma unroll
  for (int i = 0; i < 4; ++i) {
    float4 o;
    float* op = &o.x;
#pragma unroll
    for (int jj = 0; jj < 4; ++jj) {
      float v = acc[i][jj] + bvv[jj];
      if (RELU) v = fmaxf(v, 0.f);
      op[jj] = v;
    }
    *(float4*)(C + (size_t)(m0 + (ty << 2) + i) * N + cn) = o;
  }
}

// ---------------- encoded = eps*exp(0.5*logvar)+mu; kld reduce ---------------
__global__ __launch_bounds__(256) void enc_kld(const float* __restrict__ mu,
    const float* __restrict__ lv, const float* __restrict__ eps,
    float* __restrict__ enc, float* __restrict__ kld)
{
  const int idx = blockIdx.x * 256 + threadIdx.x;
  const float m = mu[idx], l = lv[idx];
  enc[idx] = eps[idx] * expf(0.5f * l) + m;
  float term = 1.0f + l - m * m - expf(l);
  __shared__ float red[256];
  red[threadIdx.x] = term;
  __syncthreads();
  for (int s = 128; s > 0; s >>= 1) {
    if (threadIdx.x < s) red[threadIdx.x] += red[threadIdx.x + s];
    __syncthreads();
  }
  if (threadIdx.x == 0) atomicAdd(kld, -0.5f * red[0] / (float)kB);
}

// ---------------- W_comb = w_ih0 @ d_fc2w (bf16 out); b_comb; gvec0 ----------
__global__ __launch_bounds__(256) void prep_comb(const float* __restrict__ wih0,
    const float* __restrict__ bih0, const float* __restrict__ fc2w,
    const float* __restrict__ fc2b, unsigned short* __restrict__ Wcb,
    float* __restrict__ bc, float* __restrict__ g0)
{
  const int idx = blockIdx.x * 256 + threadIdx.x;   // < 1536*512
  const int n = idx >> 9, j = idx & 511;
  float s = 0.f;
#pragma unroll
  for (int v = 0; v < kV; ++v) s = fmaf(wih0[n * kV + v], fc2w[v * kH + j], s);
  Wcb[idx] = f2bf(s);
  if (j == 0) {
    float sb = 0.f;
    for (int v = 0; v < kV; ++v) sb = fmaf(wih0[n * kV + v], fc2b[v], sb);
    bc[n] = bih0[n] + sb;
  }
  if (j == 1) g0[n] = wih0[n * kV + 41] + bih0[n];
}

__global__ __launch_bounds__(256) void conv_bf16(const float* __restrict__ s,
                                                 unsigned short* __restrict__ d, int n)
{
  const int i = blockIdx.x * 256 + threadIdx.x;
  if (i < n) d[i] = f2bf(s[i]);
}

__global__ __launch_bounds__(256) void conv_fc2w_pad(const float* __restrict__ fc2w,
                                                     unsigned short* __restrict__ d)
{
  const int i = blockIdx.x * 256 + threadIdx.x;   // < 48*512
  if (i < 48 * kH) {
    const int r = i >> 9, k = i & 511;
    d[i] = (r < kV) ? f2bf(fc2w[r * kH + k]) : 0;
  }
}

// ---------------- persistent MFMA GRU, LDS weights + leader mg barriers ------
// 256 blocks x 1024 threads. jg = bid>>2 (64 x 8 js), mg = bid&3 (128 batches).
//   waves 0-7:  phase A = T1 (gh0) from CARRIED ar[16] regs (no load);
//               phase B = gi1: ld_row16(h0n) -> ar (persists to next step).
//   waves 8-15: phase A = T0 (gi0|gh1): ld_row16(h1c) -> ar, MFMA;
//               phase B = out-projection (jg<3): REUSES ar (same h1c rows,
//               ar untouched since phase A) -> no reload, no straggler.
// Gate biases in a 480B LDS table.
__global__ __launch_bounds__(1024) void gru_mfma(
    const unsigned short* __restrict__ Wcb, const unsigned short* __restrict__ whh0b,
    const unsigned short* __restrict__ wih1b, const unsigned short* __restrict__ whh1b,
    const unsigned short* __restrict__ fc2wb,
    const float* __restrict__ bc, const float* __restrict__ g0,
    const float* __restrict__ bhh0, const float* __restrict__ bih1,
    const float* __restrict__ bhh1, const float* __restrict__ fc2b,
    const float* __restrict__ latg,
    unsigned short* h0A, unsigned short* h0B,
    unsigned short* h1A, unsigned short* h1B,
    float* __restrict__ out, unsigned* bar)
{
  extern __shared__ char smem[];
  unsigned short* w = (unsigned short*)smem;
  float* CsA = (float*)(smem + kCsAByte);
  float* CsB = CsA + 7680;
  float* bt  = CsB + 3840;   // bias table: 15 rows x 8 jl

  const int tid = threadIdx.x;
  const int wave = tid >> 6;
  const int lane = tid & 63;
  const int quad = lane >> 4;
  const int flr  = lane & 15;
  const int q8   = quad * 8;
  const int bid = blockIdx.x;
  const int jg = bid >> 2, mg = bid & 3;
  const int jbase = jg * 8;
  const int m0 = mg * 128;

  // ---- one-time weight staging into LDS ----
  for (int c = tid; c < kWRows * 64; c += 1024) {
    const int row = c >> 6;
    const int k8 = (c & 63) << 3;
    const unsigned short* src;
    int srow;
    if (row < 48) {
      const int g = row >> 4, n = row & 15;
      srow = g * kH + jbase + (n & 7);
      src = (n < 8) ? Wcb : whh1b;
    } else if (row < 72) {
      const int rr = row - 48;
      srow = (rr >> 3) * kH + jbase + (rr & 7);
      src = whh0b;
    } else {
      const int rr = row - 72;
      srow = (rr >> 3) * kH + jbase + (rr & 7);
      src = wih1b;
    }
    *(uint4*)&w[row * kWPitch + k8] = *(const uint4*)&src[(size_t)srow * kH + k8];
  }
  if (tid < 32) w[kZPad + tid] = 0;

  // ---- bias table into LDS (15 x 8) ----
  if (tid < 120) {
    const int r = tid >> 3, jjl = tid & 7;
    const int jj = jbase + jjl;
    float v;
    if (r < 3)       v = g0[r * kH + jj];
    else if (r < 6)  v = bc[(r - 3) * kH + jj];
    else if (r < 9)  v = bhh0[(r - 6) * kH + jj];
    else if (r < 12) v = bih1[(r - 9) * kH + jj];
    else             v = bhh1[(r - 12) * kH + jj];
    bt[tid] = v;
  }

  // step-invariant LDS B-frag offsets (bf16 units)
  int boffT0[3], boffT1[3], boffB[3];
#pragma unroll
  for (int g = 0; g < 3; ++g) {
    boffT0[g] = (g * 16 + flr) * kWPitch + q8;
    boffT1[g] = (flr < 8) ? (48 + g * 8 + flr) * kWPitch + q8 : kZPad + q8;
    boffB[g]  = (flr < 8) ? (72 + g * 8 + flr) * kWPitch + q8 : kZPad + q8;
  }

  // gate-math mapping: one item per thread: m = tid>>3 (0..127), jl = tid&7
  const int gm = tid >> 3;
  const int jl = tid & 7;
  const int gmt = gm >> 4, gml = gm & 15;
  const int j = jbase + jl;

  float hp0 = latg[(size_t)(m0 + gm) * kH + j];
  float hp1 = 0.f;

  const bool isProj = (jg < 3) && (wave >= 8);
  const int pv = jg * 16 + flr;
  const float fbv = (isProj && pv < kV) ? fc2b[pv] : 0.f;

  __syncthreads();

  const unsigned short* h0c = h0A; unsigned short* h0n_ = h0B;
  const unsigned short* h1c = h1A; unsigned short* h1n_ = h1B;
  const f32x4 zf = {0.f, 0.f, 0.f, 0.f};

  // shared A-fragment array: persistent h0 carry (waves 0-7) /
  // h1c tile (waves 8-15, reused by projection)
  bf16x8 ar[16];
  if (wave < 8) {
    const unsigned short* ap0 = h0c + (size_t)(m0 + wave * 16 + flr) * kH + q8;
    ld_row16(ap0, ar);     // initial h0 state (latg bf16)
  }

  for (int t = 0; t < kSEQ; ++t) {
    // ---------- phase A ----------
    if (wave >= 8) {          // T0: gi0|gh1, A = h1c (fresh load into ar)
      const int wv = wave - 8;
      const unsigned short* ap = h1c + (size_t)(m0 + wv * 16 + flr) * kH + q8;
      ld_row16(ap, ar);
      f32x4 acc[3] = {zf, zf, zf};
#pragma unroll
      for (int kf = 0; kf < 16; ++kf) {
        const int ko = kf * 32;
#pragma unroll
        for (int g = 0; g < 3; ++g)
          acc[g] = __builtin_amdgcn_mfma_f32_16x16x32_bf16(
              ar[kf], *(const bf16x8*)&w[boffT0[g] + ko], acc[g], 0, 0, 0);
      }
#pragma unroll
      for (int g = 0; g < 3; ++g)
        *(f32x4*)&CsA[((g * 8 + wv) * 16 + flr) * 20 + quad * 4] = acc[g];
    } else {                  // T1: gh0, A = CARRIED h0 frags (no load!)
      f32x4 acc[3] = {zf, zf, zf};
#pragma unroll
      for (int kf = 0; kf < 16; ++kf) {
        const int ko = kf * 32;
#pragma unroll
        for (int g = 0; g < 3; ++g)
          acc[g] = __builtin_amdgcn_mfma_f32_16x16x32_bf16(
              ar[kf], *(const bf16x8*)&w[boffT1[g] + ko], acc[g], 0, 0, 0);
      }
      if (flr < 8) {
#pragma unroll
        for (int g = 0; g < 3; ++g)
          *(f32x4*)&CsB[((g * 8 + wave) * 8 + flr) * 20 + quad * 4] = acc[g];
      }
    }
    __syncthreads();
    // ---------- gate L0 (1024 threads x 1 item) ----------
    {
      const float gir = CsA[((0 * 8 + gmt) * 16 + jl) * 20 + gml] + bt[(t == 0 ? 0 : 3) * 8 + jl];
      const float giz = CsA[((1 * 8 + gmt) * 16 + jl) * 20 + gml] + bt[(t == 0 ? 1 : 4) * 8 + jl];
      const float gin = CsA[((2 * 8 + gmt) * 16 + jl) * 20 + gml] + bt[(t == 0 ? 2 : 5) * 8 + jl];
      const float ghr = CsB[((0 * 8 + gmt) * 8 + jl) * 20 + gml] + bt[6 * 8 + jl];
      const float ghz = CsB[((1 * 8 + gmt) * 8 + jl) * 20 + gml] + bt[7 * 8 + jl];
      const float ghn = CsB[((2 * 8 + gmt) * 8 + jl) * 20 + gml] + bt[8 * 8 + jl];
      const float r = sigm(gir + ghr);
      const float z = sigm(giz + ghz);
      const float n = tanhf(gin + r * ghn);
      const float h = (1.f - z) * n + z * hp0;
      hp0 = h;
      st_h2(h0n_ + (size_t)(m0 + gm) * kH + j, f2bf(h));
    }
    mg_barrier(bar, (unsigned)(2 * t + 1), mg, jg, wave, lane);
    // ---------- phase B ----------
    if (wave < 8) {           // gi1: A = h0n -> load into ar, KEEP for next step
      const unsigned short* ap = h0n_ + (size_t)(m0 + wave * 16 + flr) * kH + q8;
      ld_row16(ap, ar);
      f32x4 acc[3] = {zf, zf, zf};
#pragma unroll
      for (int kf = 0; kf < 16; ++kf) {
        const int ko = kf * 32;
#pragma unroll
        for (int g = 0; g < 3; ++g)
          acc[g] = __builtin_amdgcn_mfma_f32_16x16x32_bf16(
              ar[kf], *(const bf16x8*)&w[boffB[g] + ko], acc[g], 0, 0, 0);
      }
      if (flr < 8) {
#pragma unroll
        for (int g = 0; g < 3; ++g)
          *(f32x4*)&CsB[((g * 8 + wave) * 8 + flr) * 20 + quad * 4] = acc[g];
      }
    } else if (isProj && t > 0) {   // out(t-1) = h1(t-1) @ fc2w^T, ar REUSED
      const int mt = wave - 8;
      const unsigned short* bp = fc2wb + (size_t)(jg * 16 + flr) * kH + q8;
      f32x4 pa = zf;
#pragma unroll
      for (int kf = 0; kf < 16; ++kf) {
        const int ko = kf * 32;
        pa = __builtin_amdgcn_mfma_f32_16x16x32_bf16(
            ar[kf], *(const bf16x8*)(bp + ko), pa, 0, 0, 0);
      }
      if (pv < kV) {
#pragma unroll
        for (int r = 0; r < 4; ++r)
          out[(size_t)(m0 + mt * 16 + quad * 4 + r) * (kSEQ * kV)
              + (size_t)(t - 1) * kV + pv] = pa[r] + fbv;
      }
    }
    __syncthreads();
    // ---------- gate L1 (1024 threads x 1 item) ----------
    {
      const float gir = CsB[((0 * 8 + gmt) * 8 + jl) * 20 + gml] + bt[9 * 8 + jl];
      const float giz = CsB[((1 * 8 + gmt) * 8 + jl) * 20 + gml] + bt[10 * 8 + jl];
      const float gin = CsB[((2 * 8 + gmt) * 8 + jl) * 20 + gml] + bt[11 * 8 + jl];
      const float ghr = CsA[((0 * 8 + gmt) * 16 + 8 + jl) * 20 + gml] + bt[12 * 8 + jl];
      const float ghz = CsA[((1 * 8 + gmt) * 16 + 8 + jl) * 20 + gml] + bt[13 * 8 + jl];
      const float ghn = CsA[((2 * 8 + gmt) * 16 + 8 + jl) * 20 + gml] + bt[14 * 8 + jl];
      const float r = sigm(gir + ghr);
      const float z = sigm(giz + ghz);
      const float n = tanhf(gin + r * ghn);
      const float h = (1.f - z) * n + z * hp1;
      hp1 = h;
      st_h2(h1n_ + (size_t)(m0 + gm) * kH + j, f2bf(h));
    }
    mg_barrier(bar, (unsigned)(2 * t + 2), mg, jg, wave, lane);
    {
      const unsigned short* tc;
      tc = h0c; h0c = h0n_; h0n_ = (unsigned short*)tc;
      tc = h1c; h1c = h1n_; h1n_ = (unsigned short*)tc;
    }
  }
  // ---------- tail projection: out[127] from final h1 (buffer swapped -> load)
  if (isProj) {
    const int mt = wave - 8;
    const unsigned short* ap = h1c + (size_t)(m0 + mt * 16 + flr) * kH + q8;
    const unsigned short* bp = fc2wb + (size_t)(jg * 16 + flr) * kH + q8;
    ld_row16(ap, ar);
    f32x4 pa = zf;
#pragma unroll
    for (int kf = 0; kf < 16; ++kf) {
      const int ko = kf * 32;
      pa = __builtin_amdgcn_mfma_f32_16x16x32_bf16(
          ar[kf], *(const bf16x8*)(bp + ko), pa, 0, 0, 0);
    }
    if (pv < kV) {
#pragma unroll
      for (int r = 0; r < 4; ++r)
        out[(size_t)(m0 + mt * 16 + quad * 4 + r) * (kSEQ * kV)
            + (size_t)(kSEQ - 1) * kV + pv] = pa[r] + fbv;
    }
  }
}

extern "C" void kernel_launch(void* const* d_in, const int* in_sizes, int n_in,
                              void* d_out, int out_size, void* d_ws, size_t ws_size,
                              hipStream_t stream) {
  const float* X    = (const float*)d_in[0];
  const float* eps  = (const float*)d_in[2];
  const float* e1w  = (const float*)d_in[3];  const float* e1b  = (const float*)d_in[4];
  const float* e2w  = (const float*)d_in[5];  const float* e2b  = (const float*)d_in[6];
  const float* e3w  = (const float*)d_in[7];  const float* e3b  = (const float*)d_in[8];
  const float* e41w = (const float*)d_in[9];  const float* e41b = (const float*)d_in[10];
  const float* e42w = (const float*)d_in[11]; const float* e42b = (const float*)d_in[12];
  const float* fc1w = (const float*)d_in[13]; const float* fc1b = (const float*)d_in[14];
  const float* fc2w = (const float*)d_in[15]; const float* fc2b = (const float*)d_in[16];
  const float* wih0 = (const float*)d_in[17]; const float* bih0 = (const float*)d_in[18];
  const float* whh0 = (const float*)d_in[19]; const float* bhh0 = (const float*)d_in[20];
  const float* wih1 = (const float*)d_in[21]; const float* bih1 = (const float*)d_in[22];
  const float* whh1 = (const float*)d_in[23]; const float* bhh1 = (const float*)d_in[24];
  float* out = (float*)d_out;

  float* ws = (float*)d_ws;
  float* eh1 = ws;
  unsigned short* Wcb   = (unsigned short*)(ws + 0);        // 786432 us
  unsigned short* whh0b = (unsigned short*)(ws + 393216);   // 786432 us
  unsigned short* fc2wb = (unsigned short*)(ws + 786432);   // 24576 us
  float* eh2 = ws + 1048576;
  unsigned short* wih1b = (unsigned short*)(ws + 1048576);  // 786432 us
  unsigned short* whh1b = (unsigned short*)(ws + 1441792);  // 786432 us
  float* eh3 = ws + 1572864;
  float* latg = ws + 1835008;                               // 262144 f
  unsigned short* h0a = (unsigned short*)(ws + 2097152);
  unsigned short* h0b = (unsigned short*)(ws + 2228224);
  unsigned short* h1a = (unsigned short*)(ws + 2359296);
  unsigned short* h1b = (unsigned short*)(ws + 2490368);
  float* mu  = ws + 2621440;
  float* lv  = ws + 2654208;
  float* enc = ws + 2686976;
  float* bc  = ws + 2719744;
  float* g0  = ws + 2721280;
  unsigned* bar = (unsigned*)(ws + 2723840);                // 5120 u32 (20 KB)

  const size_t dec_elems = (size_t)kB * kSEQ * kV;

  // ---- encoder ----
  gemm_bias<true ><<<dim3(32, 8), 256, 0, stream>>>(X,   e1w, e1b, eh1, kB, 2048, 4096);
  gemm_bias<true ><<<dim3(16, 8), 256, 0, stream>>>(eh1, e2w, e2b, eh2, kB, 1024, 2048);
  gemm_bias<true ><<<dim3( 8, 8), 256, 0, stream>>>(eh2, e3w, e3b, eh3, kB,  512, 1024);
  gemm_bias<false><<<dim3( 1, 8), 256, 0, stream>>>(eh3, e41w, e41b, mu, kB,   64,  512);
  gemm_bias<false><<<dim3( 1, 8), 256, 0, stream>>>(eh3, e42w, e42b, lv, kB,   64,  512);
  hipMemsetAsync(out + dec_elems, 0, sizeof(float), stream);
  enc_kld<<<128, 256, 0, stream>>>(mu, lv, eps, enc, out + dec_elems);
  gemm_bias<false><<<dim3(8, 8), 256, 0, stream>>>(enc, fc1w, fc1b, latg, kB, kH, kENC);

  // ---- weight prep (bf16) + barrier init ----
  prep_comb<<<3072, 256, 0, stream>>>(wih0, bih0, fc2w, fc2b, Wcb, bc, g0);
  conv_bf16<<<3072, 256, 0, stream>>>(whh0, whh0b, 1536 * kH);
  conv_bf16<<<3072, 256, 0, stream>>>(wih1, wih1b, 1536 * kH);
  conv_bf16<<<3072, 256, 0, stream>>>(whh1, whh1b, 1536 * kH);
  conv_fc2w_pad<<<96, 256, 0, stream>>>(fc2w, fc2wb);
  conv_bf16<<<1024, 256, 0, stream>>>(latg, h0a, kB * kH);
  hipMemsetAsync(h1a, 0, (size_t)kB * kH * sizeof(unsigned short), stream);
  hipMemsetAsync(bar, 0, 20480, stream);

  // ---- persistent MFMA GRU decoder ----
  hipFuncSetAttribute((const void*)gru_mfma,
                      hipFuncAttributeMaxDynamicSharedMemorySize, kLdsBytes);
  void* args[] = { (void*)&Wcb, (void*)&whh0b, (void*)&wih1b, (void*)&whh1b,
                   (void*)&fc2wb, (void*)&bc, (void*)&g0, (void*)&bhh0,
                   (void*)&bih1, (void*)&bhh1, (void*)&fc2b, (void*)&latg,
                   (void*)&h0a, (void*)&h0b, (void*)&h1a, (void*)&h1b,
                   (void*)&out, (void*)&bar };
  hipLaunchCooperativeKernel((void*)gru_mfma, dim3(256), dim3(1024), args,
                             kLdsBytes, stream);
}

// Round 12
// 3515.026 us; speedup vs baseline: 1.0302x; 1.0302x over previous
//
#include <hip/hip_runtime.h>
#include <math.h>

constexpr int kB = 512, kENC = 64, kH = 512, kV = 42, kSEQ = 128;
constexpr int kWPitch = 520;                    // bf16 LDS row pitch (bank-skewed)
constexpr int kWRows  = 96;                     // 48 T0 (Wc|whh1) + 24 whh0 + 24 wih1
constexpr int kZPad   = kWRows * kWPitch;       // 49920: 32 bf16 zeros
constexpr int kCsAByte = (kZPad + 32) * 2;      // 99904
// CsA 7680 f32 + CsB 3840 f32 + bias table 120 f32
constexpr int kLdsBytes = kCsAByte + 30720 + 15360 + 480;  // 146464

typedef __attribute__((ext_vector_type(8))) short bf16x8;
typedef __attribute__((ext_vector_type(4))) float f32x4;
typedef unsigned long long u64;

__device__ __forceinline__ unsigned short f2bf(float x) {
  union { float f; unsigned u; } c; c.f = x;
  unsigned r = c.u + 0x7FFFu + ((c.u >> 16) & 1u);
  return (unsigned short)(r >> 16);
}
__device__ __forceinline__ float sigm(float x) { return 1.f / (1.f + expf(-x)); }

// Batched LLC-coherent A-row fetch: 16x global_load_dwordx4 sc0 sc1 (L1/L2
// bypass, coherent point) in ONE asm block, vmcnt(0) inside. R2-proven: 16
// loads in flight -> one LLC latency per phase instead of 16. Measured
// refutations: L2-cached+inv (R9, +8%), leader barrier (R11, +4%),
// coalesced publish (R8, +4%), L2+full fences (R3, +35%).
__device__ __forceinline__ void ld_row16(const unsigned short* p, bf16x8 (&r)[16]) {
  asm volatile(
    "global_load_dwordx4 %0, %16, off sc0 sc1\n\t"
    "global_load_dwordx4 %1, %16, off offset:64 sc0 sc1\n\t"
    "global_load_dwordx4 %2, %16, off offset:128 sc0 sc1\n\t"
    "global_load_dwordx4 %3, %16, off offset:192 sc0 sc1\n\t"
    "global_load_dwordx4 %4, %16, off offset:256 sc0 sc1\n\t"
    "global_load_dwordx4 %5, %16, off offset:320 sc0 sc1\n\t"
    "global_load_dwordx4 %6, %16, off offset:384 sc0 sc1\n\t"
    "global_load_dwordx4 %7, %16, off offset:448 sc0 sc1\n\t"
    "global_load_dwordx4 %8, %16, off offset:512 sc0 sc1\n\t"
    "global_load_dwordx4 %9, %16, off offset:576 sc0 sc1\n\t"
    "global_load_dwordx4 %10, %16, off offset:640 sc0 sc1\n\t"
    "global_load_dwordx4 %11, %16, off offset:704 sc0 sc1\n\t"
    "global_load_dwordx4 %12, %16, off offset:768 sc0 sc1\n\t"
    "global_load_dwordx4 %13, %16, off offset:832 sc0 sc1\n\t"
    "global_load_dwordx4 %14, %16, off offset:896 sc0 sc1\n\t"
    "global_load_dwordx4 %15, %16, off offset:960 sc0 sc1\n\t"
    "s_waitcnt vmcnt(0)"
    : "=&v"(r[0]), "=&v"(r[1]), "=&v"(r[2]), "=&v"(r[3]),
      "=&v"(r[4]), "=&v"(r[5]), "=&v"(r[6]), "=&v"(r[7]),
      "=&v"(r[8]), "=&v"(r[9]), "=&v"(r[10]), "=&v"(r[11]),
      "=&v"(r[12]), "=&v"(r[13]), "=&v"(r[14]), "=&v"(r[15])
    : "v"(p)
    : "memory");
}

// agent-scope (LLC-coherent, L1/L2-bypass) h-state store (R8: coalesced
// staging is a regression — the fabric already write-combines this scatter).
__device__ __forceinline__ void st_h2(unsigned short* p, unsigned short v) {
  __hip_atomic_store(p, v, __ATOMIC_RELAXED, __HIP_MEMORY_SCOPE_AGENT);
}

// FLAT single-hop mg-group barrier (best measured: R5/R10, 2987us steady;
// leader-aggregated variant R11 = +4%):
// - each of the 64 blocks in the mg group owns one padded slot; arrival =
//   one release-store of the event number (no RMW chain).
// - detection: the 64 lanes of wave 0 each poll ONE slot; loop exits when
//   all slots >= ev. Critical path ~2 LLC RTTs.
// __syncthreads() before arrival drains every wave's h-state stores.
__device__ __forceinline__ void mg_barrier(unsigned* bar, unsigned ev, int mg,
                                           int jg, int wave, int lane) {
  __syncthreads();
  if (wave == 0) {
    if (lane == 0)
      __hip_atomic_store(&bar[(mg * 64 + jg) * 16], ev,
                         __ATOMIC_RELEASE, __HIP_MEMORY_SCOPE_AGENT);
    const unsigned* sl = &bar[(mg * 64 + lane) * 16];
    while (__hip_atomic_load(sl, __ATOMIC_RELAXED, __HIP_MEMORY_SCOPE_AGENT) < ev)
      __builtin_amdgcn_s_sleep(1);
    (void)__hip_atomic_load(sl, __ATOMIC_ACQUIRE, __HIP_MEMORY_SCOPE_AGENT);
  }
  __syncthreads();
}

// ---------------- generic SGEMM: C[M,N] = act(A[M,K] @ W[N,K]^T + bias[N]) ----
template<bool RELU>
__global__ __launch_bounds__(256) void gemm_bias(const float* __restrict__ A,
    const float* __restrict__ W, const float* __restrict__ bias,
    float* __restrict__ C, int M, int N, int K)
{
  __shared__ float As[16][68];
  __shared__ float Bs[16][68];
  const int tid = threadIdx.x;
  const int n0 = blockIdx.x * 64;
  const int m0 = blockIdx.y * 64;
  const int tx = tid & 15;
  const int ty = tid >> 4;
  const int lr = tid >> 2;
  const int lk = (tid & 3) << 2;
  float acc[4][4] = {};
  for (int kc = 0; kc < K; kc += 16) {
    const float4 va = *(const float4*)(A + (size_t)(m0 + lr) * K + kc + lk);
    const float4 vb = *(const float4*)(W + (size_t)(n0 + lr) * K + kc + lk);
    __syncthreads();
    As[lk+0][lr] = va.x; As[lk+1][lr] = va.y; As[lk+2][lr] = va.z; As[lk+3][lr] = va.w;
    Bs[lk+0][lr] = vb.x; Bs[lk+1][lr] = vb.y; Bs[lk+2][lr] = vb.z; Bs[lk+3][lr] = vb.w;
    __syncthreads();
#pragma unroll
    for (int k = 0; k < 16; ++k) {
      const float4 a = *(const float4*)&As[k][ty << 2];
      const float4 b = *(const float4*)&Bs[k][tx << 2];
      const float av[4] = {a.x, a.y, a.z, a.w};
      const float bv[4] = {b.x, b.y, b.z, b.w};
#pragma unroll
      for (int i = 0; i < 4; ++i)
#pragma unroll
        for (int jj = 0; jj < 4; ++jj) acc[i][jj] = fmaf(av[i], bv[jj], acc[i][jj]);
    }
  }
  const int cn = n0 + (tx << 2);
  const float4 b4 = *(const float4*)&bias[cn];
  const float bvv[4] = {b4.x, b4.y, b4.z, b4.w};
#pragma unroll
  for (int i = 0; i < 4; ++i) {
    float4 o;
    float* op = &o.x;
#pragma unroll
    for (int jj = 0; jj < 4; ++jj) {
      float v = acc[i][jj] + bvv[jj];
      if (RELU) v = fmaxf(v, 0.f);
      op[jj] = v;
    }
    *(float4*)(C + (size_t)(m0 + (ty << 2) + i) * N + cn) = o;
  }
}

// ---------------- encoded = eps*exp(0.5*logvar)+mu; kld reduce ---------------
__global__ __launch_bounds__(256) void enc_kld(const float* __restrict__ mu,
    const float* __restrict__ lv, const float* __restrict__ eps,
    float* __restrict__ enc, float* __restrict__ kld)
{
  const int idx = blockIdx.x * 256 + threadIdx.x;
  const float m = mu[idx], l = lv[idx];
  enc[idx] = eps[idx] * expf(0.5f * l) + m;
  float term = 1.0f + l - m * m - expf(l);
  __shared__ float red[256];
  red[threadIdx.x] = term;
  __syncthreads();
  for (int s = 128; s > 0; s >>= 1) {
    if (threadIdx.x < s) red[threadIdx.x] += red[threadIdx.x + s];
    __syncthreads();
  }
  if (threadIdx.x == 0) atomicAdd(kld, -0.5f * red[0] / (float)kB);
}

// ---------------- W_comb = w_ih0 @ d_fc2w (bf16 out); b_comb; gvec0 ----------
__global__ __launch_bounds__(256) void prep_comb(const float* __restrict__ wih0,
    const float* __restrict__ bih0, const float* __restrict__ fc2w,
    const float* __restrict__ fc2b, unsigned short* __restrict__ Wcb,
    float* __restrict__ bc, float* __restrict__ g0)
{
  const int idx = blockIdx.x * 256 + threadIdx.x;   // < 1536*512
  const int n = idx >> 9, j = idx & 511;
  float s = 0.f;
#pragma unroll
  for (int v = 0; v < kV; ++v) s = fmaf(wih0[n * kV + v], fc2w[v * kH + j], s);
  Wcb[idx] = f2bf(s);
  if (j == 0) {
    float sb = 0.f;
    for (int v = 0; v < kV; ++v) sb = fmaf(wih0[n * kV + v], fc2b[v], sb);
    bc[n] = bih0[n] + sb;
  }
  if (j == 1) g0[n] = wih0[n * kV + 41] + bih0[n];
}

__global__ __launch_bounds__(256) void conv_bf16(const float* __restrict__ s,
                                                 unsigned short* __restrict__ d, int n)
{
  const int i = blockIdx.x * 256 + threadIdx.x;
  if (i < n) d[i] = f2bf(s[i]);
}

__global__ __launch_bounds__(256) void conv_fc2w_pad(const float* __restrict__ fc2w,
                                                     unsigned short* __restrict__ d)
{
  const int i = blockIdx.x * 256 + threadIdx.x;   // < 48*512
  if (i < 48 * kH) {
    const int r = i >> 9, k = i & 511;
    d[i] = (r < kV) ? f2bf(fc2w[r * kH + k]) : 0;
  }
}

// ---------------- persistent MFMA GRU, LDS weights + flat mg barriers --------
// 256 blocks x 1024 threads. jg = bid>>2 (64 x 8 js), mg = bid&3 (128 batches).
//   waves 0-7:  phase A = T1 (gh0) from CARRIED ar[16] regs (no load);
//               phase B = gi1: ld_row16(h0n) -> ar (persists to next step).
//   waves 8-15: phase A = T0 (gi0|gh1): ld_row16(h1c) -> ar, MFMA;
//               phase B = out-projection (jg<3): REUSES ar (same h1c rows,
//               ar untouched since phase A) -> no reload, no straggler.
// Gate biases in a 480B LDS table.
__global__ __launch_bounds__(1024) void gru_mfma(
    const unsigned short* __restrict__ Wcb, const unsigned short* __restrict__ whh0b,
    const unsigned short* __restrict__ wih1b, const unsigned short* __restrict__ whh1b,
    const unsigned short* __restrict__ fc2wb,
    const float* __restrict__ bc, const float* __restrict__ g0,
    const float* __restrict__ bhh0, const float* __restrict__ bih1,
    const float* __restrict__ bhh1, const float* __restrict__ fc2b,
    const float* __restrict__ latg,
    unsigned short* h0A, unsigned short* h0B,
    unsigned short* h1A, unsigned short* h1B,
    float* __restrict__ out, unsigned* bar)
{
  extern __shared__ char smem[];
  unsigned short* w = (unsigned short*)smem;
  float* CsA = (float*)(smem + kCsAByte);
  float* CsB = CsA + 7680;
  float* bt  = CsB + 3840;   // bias table: 15 rows x 8 jl

  const int tid = threadIdx.x;
  const int wave = tid >> 6;
  const int lane = tid & 63;
  const int quad = lane >> 4;
  const int flr  = lane & 15;
  const int q8   = quad * 8;
  const int bid = blockIdx.x;
  const int jg = bid >> 2, mg = bid & 3;
  const int jbase = jg * 8;
  const int m0 = mg * 128;

  // ---- one-time weight staging into LDS ----
  for (int c = tid; c < kWRows * 64; c += 1024) {
    const int row = c >> 6;
    const int k8 = (c & 63) << 3;
    const unsigned short* src;
    int srow;
    if (row < 48) {
      const int g = row >> 4, n = row & 15;
      srow = g * kH + jbase + (n & 7);
      src = (n < 8) ? Wcb : whh1b;
    } else if (row < 72) {
      const int rr = row - 48;
      srow = (rr >> 3) * kH + jbase + (rr & 7);
      src = whh0b;
    } else {
      const int rr = row - 72;
      srow = (rr >> 3) * kH + jbase + (rr & 7);
      src = wih1b;
    }
    *(uint4*)&w[row * kWPitch + k8] = *(const uint4*)&src[(size_t)srow * kH + k8];
  }
  if (tid < 32) w[kZPad + tid] = 0;

  // ---- bias table into LDS (15 x 8) ----
  if (tid < 120) {
    const int r = tid >> 3, jjl = tid & 7;
    const int jj = jbase + jjl;
    float v;
    if (r < 3)       v = g0[r * kH + jj];
    else if (r < 6)  v = bc[(r - 3) * kH + jj];
    else if (r < 9)  v = bhh0[(r - 6) * kH + jj];
    else if (r < 12) v = bih1[(r - 9) * kH + jj];
    else             v = bhh1[(r - 12) * kH + jj];
    bt[tid] = v;
  }

  // step-invariant LDS B-frag offsets (bf16 units)
  int boffT0[3], boffT1[3], boffB[3];
#pragma unroll
  for (int g = 0; g < 3; ++g) {
    boffT0[g] = (g * 16 + flr) * kWPitch + q8;
    boffT1[g] = (flr < 8) ? (48 + g * 8 + flr) * kWPitch + q8 : kZPad + q8;
    boffB[g]  = (flr < 8) ? (72 + g * 8 + flr) * kWPitch + q8 : kZPad + q8;
  }

  // gate-math mapping: one item per thread: m = tid>>3 (0..127), jl = tid&7
  const int gm = tid >> 3;
  const int jl = tid & 7;
  const int gmt = gm >> 4, gml = gm & 15;
  const int j = jbase + jl;

  float hp0 = latg[(size_t)(m0 + gm) * kH + j];
  float hp1 = 0.f;

  const bool isProj = (jg < 3) && (wave >= 8);
  const int pv = jg * 16 + flr;
  const float fbv = (isProj && pv < kV) ? fc2b[pv] : 0.f;

  __syncthreads();

  const unsigned short* h0c = h0A; unsigned short* h0n_ = h0B;
  const unsigned short* h1c = h1A; unsigned short* h1n_ = h1B;
  const f32x4 zf = {0.f, 0.f, 0.f, 0.f};

  // shared A-fragment array: persistent h0 carry (waves 0-7) /
  // h1c tile (waves 8-15, reused by projection)
  bf16x8 ar[16];
  if (wave < 8) {
    const unsigned short* ap0 = h0c + (size_t)(m0 + wave * 16 + flr) * kH + q8;
    ld_row16(ap0, ar);     // initial h0 state (latg bf16)
  }

  for (int t = 0; t < kSEQ; ++t) {
    // ---------- phase A ----------
    if (wave >= 8) {          // T0: gi0|gh1, A = h1c (fresh load into ar)
      const int wv = wave - 8;
      const unsigned short* ap = h1c + (size_t)(m0 + wv * 16 + flr) * kH + q8;
      ld_row16(ap, ar);
      f32x4 acc[3] = {zf, zf, zf};
#pragma unroll
      for (int kf = 0; kf < 16; ++kf) {
        const int ko = kf * 32;
#pragma unroll
        for (int g = 0; g < 3; ++g)
          acc[g] = __builtin_amdgcn_mfma_f32_16x16x32_bf16(
              ar[kf], *(const bf16x8*)&w[boffT0[g] + ko], acc[g], 0, 0, 0);
      }
#pragma unroll
      for (int g = 0; g < 3; ++g)
        *(f32x4*)&CsA[((g * 8 + wv) * 16 + flr) * 20 + quad * 4] = acc[g];
    } else {                  // T1: gh0, A = CARRIED h0 frags (no load!)
      f32x4 acc[3] = {zf, zf, zf};
#pragma unroll
      for (int kf = 0; kf < 16; ++kf) {
        const int ko = kf * 32;
#pragma unroll
        for (int g = 0; g < 3; ++g)
          acc[g] = __builtin_amdgcn_mfma_f32_16x16x32_bf16(
              ar[kf], *(const bf16x8*)&w[boffT1[g] + ko], acc[g], 0, 0, 0);
      }
      if (flr < 8) {
#pragma unroll
        for (int g = 0; g < 3; ++g)
          *(f32x4*)&CsB[((g * 8 + wave) * 8 + flr) * 20 + quad * 4] = acc[g];
      }
    }
    __syncthreads();
    // ---------- gate L0 (1024 threads x 1 item) ----------
    {
      const float gir = CsA[((0 * 8 + gmt) * 16 + jl) * 20 + gml] + bt[(t == 0 ? 0 : 3) * 8 + jl];
      const float giz = CsA[((1 * 8 + gmt) * 16 + jl) * 20 + gml] + bt[(t == 0 ? 1 : 4) * 8 + jl];
      const float gin = CsA[((2 * 8 + gmt) * 16 + jl) * 20 + gml] + bt[(t == 0 ? 2 : 5) * 8 + jl];
      const float ghr = CsB[((0 * 8 + gmt) * 8 + jl) * 20 + gml] + bt[6 * 8 + jl];
      const float ghz = CsB[((1 * 8 + gmt) * 8 + jl) * 20 + gml] + bt[7 * 8 + jl];
      const float ghn = CsB[((2 * 8 + gmt) * 8 + jl) * 20 + gml] + bt[8 * 8 + jl];
      const float r = sigm(gir + ghr);
      const float z = sigm(giz + ghz);
      const float n = tanhf(gin + r * ghn);
      const float h = (1.f - z) * n + z * hp0;
      hp0 = h;
      st_h2(h0n_ + (size_t)(m0 + gm) * kH + j, f2bf(h));
    }
    mg_barrier(bar, (unsigned)(2 * t + 1), mg, jg, wave, lane);
    // ---------- phase B ----------
    if (wave < 8) {           // gi1: A = h0n -> load into ar, KEEP for next step
      const unsigned short* ap = h0n_ + (size_t)(m0 + wave * 16 + flr) * kH + q8;
      ld_row16(ap, ar);
      f32x4 acc[3] = {zf, zf, zf};
#pragma unroll
      for (int kf = 0; kf < 16; ++kf) {
        const int ko = kf * 32;
#pragma unroll
        for (int g = 0; g < 3; ++g)
          acc[g] = __builtin_amdgcn_mfma_f32_16x16x32_bf16(
              ar[kf], *(const bf16x8*)&w[boffB[g] + ko], acc[g], 0, 0, 0);
      }
      if (flr < 8) {
#pragma unroll
        for (int g = 0; g < 3; ++g)
          *(f32x4*)&CsB[((g * 8 + wave) * 8 + flr) * 20 + quad * 4] = acc[g];
      }
    } else if (isProj && t > 0) {   // out(t-1) = h1(t-1) @ fc2w^T, ar REUSED
      const int mt = wave - 8;
      const unsigned short* bp = fc2wb + (size_t)(jg * 16 + flr) * kH + q8;
      f32x4 pa = zf;
#pragma unroll
      for (int kf = 0; kf < 16; ++kf) {
        const int ko = kf * 32;
        pa = __builtin_amdgcn_mfma_f32_16x16x32_bf16(
            ar[kf], *(const bf16x8*)(bp + ko), pa, 0, 0, 0);
      }
      if (pv < kV) {
#pragma unroll
        for (int r = 0; r < 4; ++r)
          out[(size_t)(m0 + mt * 16 + quad * 4 + r) * (kSEQ * kV)
              + (size_t)(t - 1) * kV + pv] = pa[r] + fbv;
      }
    }
    __syncthreads();
    // ---------- gate L1 (1024 threads x 1 item) ----------
    {
      const float gir = CsB[((0 * 8 + gmt) * 8 + jl) * 20 + gml] + bt[9 * 8 + jl];
      const float giz = CsB[((1 * 8 + gmt) * 8 + jl) * 20 + gml] + bt[10 * 8 + jl];
      const float gin = CsB[((2 * 8 + gmt) * 8 + jl) * 20 + gml] + bt[11 * 8 + jl];
      const float ghr = CsA[((0 * 8 + gmt) * 16 + 8 + jl) * 20 + gml] + bt[12 * 8 + jl];
      const float ghz = CsA[((1 * 8 + gmt) * 16 + 8 + jl) * 20 + gml] + bt[13 * 8 + jl];
      const float ghn = CsA[((2 * 8 + gmt) * 16 + 8 + jl) * 20 + gml] + bt[14 * 8 + jl];
      const float r = sigm(gir + ghr);
      const float z = sigm(giz + ghz);
      const float n = tanhf(gin + r * ghn);
      const float h = (1.f - z) * n + z * hp1;
      hp1 = h;
      st_h2(h1n_ + (size_t)(m0 + gm) * kH + j, f2bf(h));
    }
    mg_barrier(bar, (unsigned)(2 * t + 2), mg, jg, wave, lane);
    {
      const unsigned short* tc;
      tc = h0c; h0c = h0n_; h0n_ = (unsigned short*)tc;
      tc = h1c; h1c = h1n_; h1n_ = (unsigned short*)tc;
    }
  }
  // ---------- tail projection: out[127] from final h1 (buffer swapped -> load)
  if (isProj) {
    const int mt = wave - 8;
    const unsigned short* ap = h1c + (size_t)(m0 + mt * 16 + flr) * kH + q8;
    const unsigned short* bp = fc2wb + (size_t)(jg * 16 + flr) * kH + q8;
    ld_row16(ap, ar);
    f32x4 pa = zf;
#pragma unroll
    for (int kf = 0; kf < 16; ++kf) {
      const int ko = kf * 32;
      pa = __builtin_amdgcn_mfma_f32_16x16x32_bf16(
          ar[kf], *(const bf16x8*)(bp + ko), pa, 0, 0, 0);
    }
    if (pv < kV) {
#pragma unroll
      for (int r = 0; r < 4; ++r)
        out[(size_t)(m0 + mt * 16 + quad * 4 + r) * (kSEQ * kV)
            + (size_t)(kSEQ - 1) * kV + pv] = pa[r] + fbv;
    }
  }
}

extern "C" void kernel_launch(void* const* d_in, const int* in_sizes, int n_in,
                              void* d_out, int out_size, void* d_ws, size_t ws_size,
                              hipStream_t stream) {
  const float* X    = (const float*)d_in[0];
  const float* eps  = (const float*)d_in[2];
  const float* e1w  = (const float*)d_in[3];  const float* e1b  = (const float*)d_in[4];
  const float* e2w  = (const float*)d_in[5];  const float* e2b  = (const float*)d_in[6];
  const float* e3w  = (const float*)d_in[7];  const float* e3b  = (const float*)d_in[8];
  const float* e41w = (const float*)d_in[9];  const float* e41b = (const float*)d_in[10];
  const float* e42w = (const float*)d_in[11]; const float* e42b = (const float*)d_in[12];
  const float* fc1w = (const float*)d_in[13]; const float* fc1b = (const float*)d_in[14];
  const float* fc2w = (const float*)d_in[15]; const float* fc2b = (const float*)d_in[16];
  const float* wih0 = (const float*)d_in[17]; const float* bih0 = (const float*)d_in[18];
  const float* whh0 = (const float*)d_in[19]; const float* bhh0 = (const float*)d_in[20];
  const float* wih1 = (const float*)d_in[21]; const float* bih1 = (const float*)d_in[22];
  const float* whh1 = (const float*)d_in[23]; const float* bhh1 = (const float*)d_in[24];
  float* out = (float*)d_out;

  float* ws = (float*)d_ws;
  float* eh1 = ws;
  unsigned short* Wcb   = (unsigned short*)(ws + 0);        // 786432 us
  unsigned short* whh0b = (unsigned short*)(ws + 393216);   // 786432 us
  unsigned short* fc2wb = (unsigned short*)(ws + 786432);   // 24576 us
  float* eh2 = ws + 1048576;
  unsigned short* wih1b = (unsigned short*)(ws + 1048576);  // 786432 us
  unsigned short* whh1b = (unsigned short*)(ws + 1441792);  // 786432 us
  float* eh3 = ws + 1572864;
  float* latg = ws + 1835008;                               // 262144 f
  unsigned short* h0a = (unsigned short*)(ws + 2097152);
  unsigned short* h0b = (unsigned short*)(ws + 2228224);
  unsigned short* h1a = (unsigned short*)(ws + 2359296);
  unsigned short* h1b = (unsigned short*)(ws + 2490368);
  float* mu  = ws + 2621440;
  float* lv  = ws + 2654208;
  float* enc = ws + 2686976;
  float* bc  = ws + 2719744;
  float* g0  = ws + 2721280;
  unsigned* bar = (unsigned*)(ws + 2723840);                // 4096 u32 (16 KB)

  const size_t dec_elems = (size_t)kB * kSEQ * kV;

  // ---- encoder ----
  gemm_bias<true ><<<dim3(32, 8), 256, 0, stream>>>(X,   e1w, e1b, eh1, kB, 2048, 4096);
  gemm_bias<true ><<<dim3(16, 8), 256, 0, stream>>>(eh1, e2w, e2b, eh2, kB, 1024, 2048);
  gemm_bias<true ><<<dim3( 8, 8), 256, 0, stream>>>(eh2, e3w, e3b, eh3, kB,  512, 1024);
  gemm_bias<false><<<dim3( 1, 8), 256, 0, stream>>>(eh3, e41w, e41b, mu, kB,   64,  512);
  gemm_bias<false><<<dim3( 1, 8), 256, 0, stream>>>(eh3, e42w, e42b, lv, kB,   64,  512);
  hipMemsetAsync(out + dec_elems, 0, sizeof(float), stream);
  enc_kld<<<128, 256, 0, stream>>>(mu, lv, eps, enc, out + dec_elems);
  gemm_bias<false><<<dim3(8, 8), 256, 0, stream>>>(enc, fc1w, fc1b, latg, kB, kH, kENC);

  // ---- weight prep (bf16) + barrier init ----
  prep_comb<<<3072, 256, 0, stream>>>(wih0, bih0, fc2w, fc2b, Wcb, bc, g0);
  conv_bf16<<<3072, 256, 0, stream>>>(whh0, whh0b, 1536 * kH);
  conv_bf16<<<3072, 256, 0, stream>>>(wih1, wih1b, 1536 * kH);
  conv_bf16<<<3072, 256, 0, stream>>>(whh1, whh1b, 1536 * kH);
  conv_fc2w_pad<<<96, 256, 0, stream>>>(fc2w, fc2wb);
  conv_bf16<<<1024, 256, 0, stream>>>(latg, h0a, kB * kH);
  hipMemsetAsync(h1a, 0, (size_t)kB * kH * sizeof(unsigned short), stream);
  hipMemsetAsync(bar, 0, 16384, stream);

  // ---- persistent MFMA GRU decoder ----
  hipFuncSetAttribute((const void*)gru_mfma,
                      hipFuncAttributeMaxDynamicSharedMemorySize, kLdsBytes);
  void* args[] = { (void*)&Wcb, (void*)&whh0b, (void*)&wih1b, (void*)&whh1b,
                   (void*)&fc2wb, (void*)&bc, (void*)&g0, (void*)&bhh0,
                   (void*)&bih1, (void*)&bhh1, (void*)&fc2b, (void*)&latg,
                   (void*)&h0a, (void*)&h0b, (void*)&h1a, (void*)&h1b,
                   (void*)&out, (void*)&bar };
  hipLaunchCooperativeKernel((void*)gru_mfma, dim3(256), dim3(1024), args,
                             kLdsBytes, stream);
}